// Round 1
// baseline (529.474 us; speedup 1.0000x reference)
//
#include <hip/hip_runtime.h>
#include <hip/hip_bf16.h>

typedef __bf16 bf16;
typedef __attribute__((ext_vector_type(8))) __bf16 bf16x8;
typedef __attribute__((ext_vector_type(4))) __bf16 bf16x4v;
typedef __attribute__((ext_vector_type(4))) float f32x4;

#define B_  16
#define C_  256
#define HW_ 1024

// ---------------- 1/||f[:,k]|| per (b,k) ----------------
__global__ void rnorm_kernel(const float* __restrict__ f, float* __restrict__ rn) {
  int idx = blockIdx.x * 256 + threadIdx.x;   // b*1024 + k
  int b = idx >> 10, k = idx & 1023;
  const float* p = f + (size_t)b * C_ * HW_ + k;
  float s = 0.f;
  #pragma unroll 8
  for (int c = 0; c < C_; ++c) { float v = p[(size_t)c * HW_]; s += v * v; }
  rn[idx] = 1.f / fmaxf(sqrtf(s), 1e-12f);
}

// ---------------- transpose + normalize + cast: A[b][k][c] = f[b][c][k]*rn[b][k] ----
__global__ void transpose_norm(const float* __restrict__ f, const float* __restrict__ rn,
                               bf16* __restrict__ A) {
  __shared__ float sm[32][33];
  int b = blockIdx.z, k0 = blockIdx.x * 32, c0 = blockIdx.y * 32;
  int tx = threadIdx.x, ty = threadIdx.y;
  const float* fb = f + ((size_t)b * C_ + c0) * HW_ + k0;
  #pragma unroll
  for (int r = 0; r < 4; ++r) {
    int cl = ty + r * 8;
    sm[cl][tx] = fb[(size_t)cl * HW_ + tx];
  }
  __syncthreads();
  bf16* Ab = A + ((size_t)b * HW_ + k0) * C_ + c0;
  #pragma unroll
  for (int r = 0; r < 4; ++r) {
    int kl = ty + r * 8;
    float rv = rn[b * HW_ + k0 + kl];
    Ab[(size_t)kl * C_ + tx] = (bf16)(sm[tx][kl] * rv);
  }
}

// ---------------- grouped 3x3 fusion conv, accumulated over tasks ----------------
__global__ void fusion_conv(const bf16* __restrict__ aff, const float* __restrict__ fw,
                            const float* __restrict__ fb, bf16* __restrict__ M,
                            int t, int init) {
  __shared__ float sa[1024];
  int bi = blockIdx.x;           // b*1024 + i
  int i = bi & 1023;
  int tid = threadIdx.x;
  const bf16* arow = aff + ((size_t)bi << 10);
  bf16x4v ch = ((const bf16x4v*)arow)[tid];
  sa[tid * 4 + 0] = (float)ch[0];
  sa[tid * 4 + 1] = (float)ch[1];
  sa[tid * 4 + 2] = (float)ch[2];
  sa[tid * 4 + 3] = (float)ch[3];
  float wgt[9];
  const float* wp = fw + i * 18 + t * 9;   // fusion_w[i][t][kh][kw]
  #pragma unroll
  for (int q = 0; q < 9; ++q) wgt[q] = wp[q];
  float bias = fb[i];
  __syncthreads();
  #pragma unroll
  for (int s0 = 0; s0 < 4; ++s0) {
    int s = tid + s0 * 256;
    int h = s >> 5, w = s & 31;
    float acc = 0.f;
    #pragma unroll
    for (int kh = 0; kh < 3; ++kh) {
      int hh = h + kh - 1;
      if ((unsigned)hh < 32u) {
        #pragma unroll
        for (int kw = 0; kw < 3; ++kw) {
          int ww = w + kw - 1;
          if ((unsigned)ww < 32u) acc += wgt[kh * 3 + kw] * sa[hh * 32 + ww];
        }
      }
    }
    size_t o = ((size_t)bi << 10) + s;
    if (init) M[o] = (bf16)(acc + bias);
    else      M[o] = (bf16)((float)M[o] + acc);
  }
}

// ---------------- im2col: patches[b][j][cin*9+d] = f[b][cin][j shifted by d] ----------------
__global__ void im2col_kernel(const float* __restrict__ f, bf16* __restrict__ p) {
  int idx = blockIdx.x * 256 + threadIdx.x;  // < 16*1024*2304
  int kk = idx % 2304;
  int bj = idx / 2304;
  int j = bj & 1023, b = bj >> 10;
  int cin = kk / 9, d = kk % 9;
  int kh = d / 3, kw = d % 3;
  int h = (j >> 5) + kh - 1, w = (j & 31) + kw - 1;
  float v = 0.f;
  if ((unsigned)h < 32u && (unsigned)w < 32u)
    v = f[((size_t)b * C_ + cin) * HW_ + h * 32 + w];
  p[idx] = (bf16)v;
}

// ---------------- fp32 -> bf16 cast ----------------
__global__ void cast_kernel(const float* __restrict__ x, bf16* __restrict__ y, int n) {
  int i = blockIdx.x * 256 + threadIdx.x;
  if (i < n) y[i] = (bf16)x[i];
}

// ---------------- NT GEMM: C[m,n] = sum_k A[m,k]*B[n,k], 128x128 tile, MFMA 16x16x32 bf16 ----
// MODE 0: store bf16 C. MODE 1: store bf16 (C + bias[row]). MODE 2: store fp32 0.5*C + 0.5*feat.
template<int MODE>
__global__ __launch_bounds__(256)
void gemm_nt(const bf16* __restrict__ A, const bf16* __restrict__ Bm,
             long long sA, long long sB, int K,
             bf16* __restrict__ Cb, long long sC,
             const float* __restrict__ bias,
             const float* __restrict__ feat, long long sF,
             float* __restrict__ Co, long long sCo) {
  __shared__ bf16 As[128 * 72];   // pad 64 -> 72 (row stride 144B, 16B aligned)
  __shared__ bf16 Bs[128 * 72];
  const int z = blockIdx.z;
  const bf16* Ab = A + (size_t)z * sA;
  const bf16* Bb = Bm + (size_t)z * sB;
  const int m0 = blockIdx.y * 128, n0 = blockIdx.x * 128;
  const int tid = threadIdx.x;
  const int lane = tid & 63, wave = tid >> 6;
  const int wm = (wave >> 1) * 64, wn = (wave & 1) * 64;
  const int fr = lane & 15, fq = lane >> 4;

  f32x4 acc[4][4];
  #pragma unroll
  for (int i = 0; i < 4; ++i)
    #pragma unroll
    for (int j = 0; j < 4; ++j) acc[i][j] = 0.f;

  for (int k0 = 0; k0 < K; k0 += 64) {
    #pragma unroll
    for (int s = 0; s < 4; ++s) {
      int q = tid + s * 256;            // 1024 chunks of 16B per tile
      int row = q >> 3, col = (q & 7) << 3;
      *(float4*)(&As[row * 72 + col]) = *(const float4*)(Ab + (size_t)(m0 + row) * K + (k0 + col));
      *(float4*)(&Bs[row * 72 + col]) = *(const float4*)(Bb + (size_t)(n0 + row) * K + (k0 + col));
    }
    __syncthreads();
    #pragma unroll
    for (int kk = 0; kk < 64; kk += 32) {
      bf16x8 af[4], bfr[4];
      #pragma unroll
      for (int i = 0; i < 4; ++i)
        af[i] = *(const bf16x8*)(&As[(wm + i * 16 + fr) * 72 + kk + fq * 8]);
      #pragma unroll
      for (int j = 0; j < 4; ++j)
        bfr[j] = *(const bf16x8*)(&Bs[(wn + j * 16 + fr) * 72 + kk + fq * 8]);
      #pragma unroll
      for (int i = 0; i < 4; ++i)
        #pragma unroll
        for (int j = 0; j < 4; ++j)
          acc[i][j] = __builtin_amdgcn_mfma_f32_16x16x32_bf16(af[i], bfr[j], acc[i][j], 0, 0, 0);
    }
    __syncthreads();
  }

  // epilogue: D element (reg r, lane) -> row = quad*4 + r, col = lane&15  [m89/m91 verified]
  #pragma unroll
  for (int i = 0; i < 4; ++i) {
    int rbase = m0 + wm + i * 16 + fq * 4;
    #pragma unroll
    for (int j = 0; j < 4; ++j) {
      int col = n0 + wn + j * 16 + fr;
      #pragma unroll
      for (int r = 0; r < 4; ++r) {
        int row = rbase + r;
        float v = acc[i][j][r];
        if (MODE == 0) {
          Cb[(size_t)z * sC + (size_t)row * 1024 + col] = (bf16)v;
        } else if (MODE == 1) {
          Cb[(size_t)z * sC + (size_t)row * 1024 + col] = (bf16)(v + bias[row]);
        } else {
          size_t o = (size_t)z * sCo + (size_t)row * 1024 + col;
          Co[o] = 0.5f * v + 0.5f * feat[(size_t)z * sF + (size_t)row * 1024 + col];
        }
      }
    }
  }
}

extern "C" void kernel_launch(void* const* d_in, const int* in_sizes, int n_in,
                              void* d_out, int out_size, void* d_ws, size_t ws_size,
                              hipStream_t stream) {
  const float* feats[2]  = { (const float*)d_in[0], (const float*)d_in[1] };
  const float* proj_w[2] = { (const float*)d_in[2], (const float*)d_in[4] };
  const float* proj_b[2] = { (const float*)d_in[3], (const float*)d_in[5] };
  const float* fusion_w  = (const float*)d_in[6];
  const float* fusion_b  = (const float*)d_in[7];
  float* out = (float*)d_out;

  // workspace layout (peak ~119 MB):
  //   [0, 32M)      Mbuf bf16 [16][1024][1024]
  //   [32M, ...)    phase1: rn(64K) | Anorm(8M) | aff(32M)     (per task, reused)
  //                 phase2: Wbf(1.13M) | patches(72M) | value(8M) (per task, reused)
  char* ws = (char*)d_ws;
  bf16* Mbuf = (bf16*)ws;                                    // 33,554,432 B
  char* S = ws + (size_t)33554432;
  float* rn    = (float*)S;                                  // 65,536 B
  bf16* Anorm  = (bf16*)(S + 65536);                         // 8,388,608 B
  bf16* aff    = (bf16*)(S + 65536 + 8388608);               // 33,554,432 B
  bf16* Wbf     = (bf16*)S;                                  // 1,179,648 B
  bf16* patches = (bf16*)(S + 1179648);                      // 75,497,472 B
  bf16* value   = (bf16*)(S + 1179648 + 75497472);           // 8,388,608 B

  for (int t = 0; t < 2; ++t) {
    rnorm_kernel<<<64, 256, 0, stream>>>(feats[t], rn);
    transpose_norm<<<dim3(32, 8, 16), dim3(32, 8), 0, stream>>>(feats[t], rn, Anorm);
    // aff[b][i][j] = sum_c Anorm[b][i][c] * Anorm[b][j][c]
    gemm_nt<0><<<dim3(8, 8, 16), 256, 0, stream>>>(
        Anorm, Anorm, (long long)HW_ * C_, (long long)HW_ * C_, C_,
        aff, (long long)HW_ * HW_, nullptr, nullptr, 0, nullptr, 0);
    fusion_conv<<<16384, 256, 0, stream>>>(aff, fusion_w, fusion_b, Mbuf, t, t == 0);
  }
  for (int t = 0; t < 2; ++t) {
    cast_kernel<<<2304, 256, 0, stream>>>(proj_w[t], Wbf, C_ * 2304);
    im2col_kernel<<<147456, 256, 0, stream>>>(feats[t], patches);
    // value[b][c][j] = sum_kk Wbf[c][kk] * patches[b][j][kk] + bias[c]
    gemm_nt<1><<<dim3(8, 2, 16), 256, 0, stream>>>(
        Wbf, patches, 0, (long long)HW_ * 2304, 2304,
        value, (long long)C_ * HW_, proj_b[t], nullptr, 0, nullptr, 0);
    // out[b][c][j] = 0.5 * sum_k value[b][c][k] * Mbuf[b][j][k] + 0.5 * f[b][c][j]
    gemm_nt<2><<<dim3(8, 2, 16), 256, 0, stream>>>(
        value, Mbuf, (long long)C_ * HW_, (long long)HW_ * HW_, HW_,
        nullptr, 0, nullptr, feats[t], (long long)C_ * HW_,
        out + (size_t)t * B_ * C_ * HW_, (long long)C_ * HW_);
  }
}

// Round 2
// 439.941 us; speedup vs baseline: 1.2035x; 1.2035x over previous
//
#include <hip/hip_runtime.h>
#include <hip/hip_bf16.h>

typedef __bf16 bf16;
typedef __attribute__((ext_vector_type(8))) __bf16 bf16x8;
typedef __attribute__((ext_vector_type(4))) __bf16 bf16x4v;
typedef __attribute__((ext_vector_type(4))) float f32x4;

#define B_  16
#define C_  256
#define HW_ 1024

// ---------------- 1/||f[:,k]|| per (b,k) ----------------
__global__ void rnorm_kernel(const float* __restrict__ f, float* __restrict__ rn) {
  int idx = blockIdx.x * 256 + threadIdx.x;   // b*1024 + k
  int b = idx >> 10, k = idx & 1023;
  const float* p = f + (size_t)b * C_ * HW_ + k;
  float s = 0.f;
  #pragma unroll 8
  for (int c = 0; c < C_; ++c) { float v = p[(size_t)c * HW_]; s += v * v; }
  rn[idx] = 1.f / fmaxf(sqrtf(s), 1e-12f);
}

// ---- transpose + cast; writes Anorm[b][k][c] = f[b][c][k]*rn[b][k] and fT[b][k][c] = f[b][c][k]
__global__ void transpose_norm(const float* __restrict__ f, const float* __restrict__ rn,
                               bf16* __restrict__ A, bf16* __restrict__ fT) {
  __shared__ float sm[32][33];
  int b = blockIdx.z, k0 = blockIdx.x * 32, c0 = blockIdx.y * 32;
  int tx = threadIdx.x, ty = threadIdx.y;
  const float* fb = f + ((size_t)b * C_ + c0) * HW_ + k0;
  #pragma unroll
  for (int r = 0; r < 4; ++r) {
    int cl = ty + r * 8;
    sm[cl][tx] = fb[(size_t)cl * HW_ + tx];
  }
  __syncthreads();
  size_t base = ((size_t)b * HW_ + k0) * C_ + c0;
  #pragma unroll
  for (int r = 0; r < 4; ++r) {
    int kl = ty + r * 8;
    float rv = rn[b * HW_ + k0 + kl];
    float v = sm[tx][kl];
    A[base + (size_t)kl * C_ + tx]  = (bf16)(v * rv);
    fT[base + (size_t)kl * C_ + tx] = (bf16)v;
  }
}

// ---------------- grouped 3x3 fusion conv, accumulated over tasks ----------------
__global__ void fusion_conv(const bf16* __restrict__ aff, const float* __restrict__ fw,
                            const float* __restrict__ fb, bf16* __restrict__ M,
                            int t, int init) {
  __shared__ float sa[1024];
  int bi = blockIdx.x;           // b*1024 + i
  int i = bi & 1023;
  int tid = threadIdx.x;
  const bf16* arow = aff + ((size_t)bi << 10);
  bf16x4v ch = ((const bf16x4v*)arow)[tid];
  sa[tid * 4 + 0] = (float)ch[0];
  sa[tid * 4 + 1] = (float)ch[1];
  sa[tid * 4 + 2] = (float)ch[2];
  sa[tid * 4 + 3] = (float)ch[3];
  float wgt[9];
  const float* wp = fw + i * 18 + t * 9;   // fusion_w[i][t][kh][kw]
  #pragma unroll
  for (int q = 0; q < 9; ++q) wgt[q] = wp[q];
  float bias = fb[i];
  __syncthreads();
  #pragma unroll
  for (int s0 = 0; s0 < 4; ++s0) {
    int s = tid + s0 * 256;
    int h = s >> 5, w = s & 31;
    float acc = 0.f;
    #pragma unroll
    for (int kh = 0; kh < 3; ++kh) {
      int hh = h + kh - 1;
      if ((unsigned)hh < 32u) {
        #pragma unroll
        for (int kw = 0; kw < 3; ++kw) {
          int ww = w + kw - 1;
          if ((unsigned)ww < 32u) acc += wgt[kh * 3 + kw] * sa[hh * 32 + ww];
        }
      }
    }
    size_t o = ((size_t)bi << 10) + s;
    if (init) M[o] = (bf16)(acc + bias);
    else      M[o] = (bf16)((float)M[o] + acc);
  }
}

// ---- weight reorder+cast: Wr[c][d*256+cin] = w[c][cin][kh][kw], d = kh*3+kw ----
__global__ void reorder_w(const float* __restrict__ x, bf16* __restrict__ y) {
  int i = blockIdx.x * 256 + threadIdx.x;   // c*2304 + cin*9 + d
  int c = i / 2304, r = i % 2304;
  int cin = r / 9, d = r % 9;
  y[c * 2304 + d * 256 + cin] = (bf16)x[i];
}

// ---------------- NT GEMM: C[m,n] = sum_k A[m,k]*B[n,k], 128x128 tile, MFMA 16x16x32 bf16 ----
// MODE 0: store bf16 C.
// MODE 1: store bf16 (C + bias[row]).
// MODE 2: store fp32 0.5*C + 0.5*feat.
// MODE 3: implicit-conv B staging (B[n][d*256+cin] = fT[b][shift_d(n)][cin]), bias epilogue.
template<int MODE>
__global__ __launch_bounds__(256)
void gemm_nt(const bf16* __restrict__ A, const bf16* __restrict__ Bm,
             long long sA, long long sB, int K,
             bf16* __restrict__ Cb, long long sC,
             const float* __restrict__ bias,
             const float* __restrict__ feat, long long sF,
             float* __restrict__ Co, long long sCo) {
  __shared__ bf16 As[128 * 72];   // pad 64 -> 72 (row stride 144B, 16B aligned)
  __shared__ bf16 Bs[128 * 72];
  const int z = blockIdx.z;
  const bf16* Ab = A + (size_t)z * sA;
  const bf16* Bb = Bm + (size_t)z * sB;
  const int m0 = blockIdx.y * 128, n0 = blockIdx.x * 128;
  const int tid = threadIdx.x;
  const int lane = tid & 63, wave = tid >> 6;
  const int wm = (wave >> 1) * 64, wn = (wave & 1) * 64;
  const int fr = lane & 15, fq = lane >> 4;

  f32x4 acc[4][4];
  #pragma unroll
  for (int i = 0; i < 4; ++i)
    #pragma unroll
    for (int j = 0; j < 4; ++j) acc[i][j] = 0.f;

  for (int k0 = 0; k0 < K; k0 += 64) {
    #pragma unroll
    for (int s = 0; s < 4; ++s) {
      int q = tid + s * 256;            // 1024 chunks of 16B per tile
      int row = q >> 3, col = (q & 7) << 3;
      *(float4*)(&As[row * 72 + col]) = *(const float4*)(Ab + (size_t)(m0 + row) * K + (k0 + col));
      if (MODE == 3) {
        // implicit im2col: d constant within this 64-wide K chunk
        int d = k0 >> 8;
        int kh = d / 3 - 1, kw = d % 3 - 1;
        int cin0 = k0 & 255;
        int j = n0 + row;
        int h = (j >> 5) + kh, w = (j & 31) + kw;
        float4 v = make_float4(0.f, 0.f, 0.f, 0.f);
        if ((unsigned)h < 32u && (unsigned)w < 32u)
          v = *(const float4*)(Bb + (size_t)(h * 32 + w) * C_ + cin0 + col);
        *(float4*)(&Bs[row * 72 + col]) = v;
      } else {
        *(float4*)(&Bs[row * 72 + col]) = *(const float4*)(Bb + (size_t)(n0 + row) * K + (k0 + col));
      }
    }
    __syncthreads();
    #pragma unroll
    for (int kk = 0; kk < 64; kk += 32) {
      bf16x8 af[4], bfr[4];
      #pragma unroll
      for (int i = 0; i < 4; ++i)
        af[i] = *(const bf16x8*)(&As[(wm + i * 16 + fr) * 72 + kk + fq * 8]);
      #pragma unroll
      for (int j = 0; j < 4; ++j)
        bfr[j] = *(const bf16x8*)(&Bs[(wn + j * 16 + fr) * 72 + kk + fq * 8]);
      #pragma unroll
      for (int i = 0; i < 4; ++i)
        #pragma unroll
        for (int j = 0; j < 4; ++j)
          acc[i][j] = __builtin_amdgcn_mfma_f32_16x16x32_bf16(af[i], bfr[j], acc[i][j], 0, 0, 0);
    }
    __syncthreads();
  }

  // epilogue: D element (reg r, lane) -> row = quad*4 + r, col = lane&15  [m89/m91 verified]
  #pragma unroll
  for (int i = 0; i < 4; ++i) {
    int rbase = m0 + wm + i * 16 + fq * 4;
    #pragma unroll
    for (int j = 0; j < 4; ++j) {
      int col = n0 + wn + j * 16 + fr;
      #pragma unroll
      for (int r = 0; r < 4; ++r) {
        int row = rbase + r;
        float v = acc[i][j][r];
        if (MODE == 0) {
          Cb[(size_t)z * sC + (size_t)row * 1024 + col] = (bf16)v;
        } else if (MODE == 1 || MODE == 3) {
          Cb[(size_t)z * sC + (size_t)row * 1024 + col] = (bf16)(v + bias[row]);
        } else {
          size_t o = (size_t)z * sCo + (size_t)row * 1024 + col;
          Co[o] = 0.5f * v + 0.5f * feat[(size_t)z * sF + (size_t)row * 1024 + col];
        }
      }
    }
  }
}

extern "C" void kernel_launch(void* const* d_in, const int* in_sizes, int n_in,
                              void* d_out, int out_size, void* d_ws, size_t ws_size,
                              hipStream_t stream) {
  const float* feats[2]  = { (const float*)d_in[0], (const float*)d_in[1] };
  const float* proj_w[2] = { (const float*)d_in[2], (const float*)d_in[4] };
  const float* proj_b[2] = { (const float*)d_in[3], (const float*)d_in[5] };
  const float* fusion_w  = (const float*)d_in[6];
  const float* fusion_b  = (const float*)d_in[7];
  float* out = (float*)d_out;

  // workspace layout (~102 MB peak):
  char* ws = (char*)d_ws;
  bf16* Mbuf  = (bf16*)ws;                               // 33,554,432 B
  bf16* aff   = (bf16*)(ws + 33554432ull);               // 33,554,432 B
  bf16* Anorm = (bf16*)(ws + 67108864ull);               //  8,388,608 B
  bf16* fT    = (bf16*)(ws + 75497472ull);               // 16,777,216 B (2 tasks)
  bf16* Wr    = (bf16*)(ws + 92274688ull);               //  1,179,648 B
  bf16* value = (bf16*)(ws + 93454336ull);               //  8,388,608 B
  float* rn   = (float*)(ws + 101842944ull);             //     65,536 B

  for (int t = 0; t < 2; ++t) {
    bf16* fTt = fT + (size_t)t * B_ * HW_ * C_;
    rnorm_kernel<<<64, 256, 0, stream>>>(feats[t], rn);
    transpose_norm<<<dim3(32, 8, 16), dim3(32, 8), 0, stream>>>(feats[t], rn, Anorm, fTt);
    // aff[b][i][j] = sum_c Anorm[b][i][c] * Anorm[b][j][c]
    gemm_nt<0><<<dim3(8, 8, 16), 256, 0, stream>>>(
        Anorm, Anorm, (long long)HW_ * C_, (long long)HW_ * C_, C_,
        aff, (long long)HW_ * HW_, nullptr, nullptr, 0, nullptr, 0);
    fusion_conv<<<16384, 256, 0, stream>>>(aff, fusion_w, fusion_b, Mbuf, t, t == 0);
  }
  for (int t = 0; t < 2; ++t) {
    bf16* fTt = fT + (size_t)t * B_ * HW_ * C_;
    reorder_w<<<2304, 256, 0, stream>>>(proj_w[t], Wr);
    // value[b][c][j] = conv(f, w)[b][c][j] + bias[c]  (implicit im2col, K = 9*256)
    gemm_nt<3><<<dim3(8, 2, 16), 256, 0, stream>>>(
        Wr, fTt, 0, (long long)HW_ * C_, 2304,
        value, (long long)C_ * HW_, proj_b[t], nullptr, 0, nullptr, 0);
    // out[b][c][j] = 0.5 * sum_k value[b][c][k] * Mbuf[b][j][k] + 0.5 * f[b][c][j]
    gemm_nt<2><<<dim3(8, 2, 16), 256, 0, stream>>>(
        value, Mbuf, (long long)C_ * HW_, (long long)HW_ * HW_, HW_,
        nullptr, 0, nullptr, feats[t], (long long)C_ * HW_,
        out + (size_t)t * B_ * C_ * HW_, (long long)C_ * HW_);
  }
}

// Round 3
// 321.692 us; speedup vs baseline: 1.6459x; 1.3676x over previous
//
#include <hip/hip_runtime.h>
#include <hip/hip_bf16.h>

typedef __bf16 bf16;
typedef __attribute__((ext_vector_type(8))) __bf16 bf16x8;
typedef __attribute__((ext_vector_type(4))) __bf16 bf16x4v;
typedef __attribute__((ext_vector_type(4))) float f32x4;

#define B_  16
#define C_  256
#define HW_ 1024

__device__ __forceinline__ void gll16(const bf16* g, bf16* l) {
  __builtin_amdgcn_global_load_lds((const __attribute__((address_space(1))) void*)g,
                                   (__attribute__((address_space(3))) void*)l, 16, 0, 0);
}

// ---------------- 1/||f[:,k]|| per (t,b,k) ----------------
__global__ void rnorm_kernel(const float* __restrict__ f0, const float* __restrict__ f1,
                             float* __restrict__ rn) {
  int idx = blockIdx.x * 256 + threadIdx.x;   // [0, 32768): t*16384 + b*1024 + k
  int t = idx >> 14, rest = idx & 16383;
  int b = rest >> 10, k = rest & 1023;
  const float* p = (t ? f1 : f0) + (size_t)b * C_ * HW_ + k;
  float s = 0.f;
  #pragma unroll 8
  for (int c = 0; c < C_; ++c) { float v = p[(size_t)c * HW_]; s += v * v; }
  rn[idx] = 1.f / fmaxf(sqrtf(s), 1e-12f);
}

// ---- transpose + cast; Anorm[z][k][c] = f[z][c][k]*rn[z][k], fT[z][k][c] = f[z][c][k]
__global__ void transpose_norm(const float* __restrict__ f0, const float* __restrict__ f1,
                               const float* __restrict__ rn,
                               bf16* __restrict__ A, bf16* __restrict__ fT) {
  __shared__ float sm[32][33];
  int z = blockIdx.z, t = z >> 4, b = z & 15;
  int k0 = blockIdx.x * 32, c0 = blockIdx.y * 32;
  int tx = threadIdx.x, ty = threadIdx.y;
  const float* fb = (t ? f1 : f0) + ((size_t)b * C_ + c0) * HW_ + k0;
  #pragma unroll
  for (int r = 0; r < 4; ++r) {
    int cl = ty + r * 8;
    sm[cl][tx] = fb[(size_t)cl * HW_ + tx];
  }
  __syncthreads();
  size_t base = ((size_t)z * HW_ + k0) * C_ + c0;
  #pragma unroll
  for (int r = 0; r < 4; ++r) {
    int kl = ty + r * 8;
    float rv = rn[z * 1024 + k0 + kl];
    float v = sm[tx][kl];
    A[base + (size_t)kl * C_ + tx]  = (bf16)(v * rv);
    fT[base + (size_t)kl * C_ + tx] = (bf16)v;
  }
}

// ---------------- grouped 3x3 fusion conv, accumulated over tasks ----------------
__global__ void fusion_conv(const bf16* __restrict__ aff, const float* __restrict__ fw,
                            const float* __restrict__ fb, bf16* __restrict__ M,
                            int t, int init) {
  __shared__ float sa[1024];
  int bi = blockIdx.x;           // b*1024 + i
  int i = bi & 1023;
  int tid = threadIdx.x;
  const bf16* arow = aff + ((size_t)bi << 10);
  bf16x4v ch = ((const bf16x4v*)arow)[tid];
  sa[tid * 4 + 0] = (float)ch[0];
  sa[tid * 4 + 1] = (float)ch[1];
  sa[tid * 4 + 2] = (float)ch[2];
  sa[tid * 4 + 3] = (float)ch[3];
  float wgt[9];
  const float* wp = fw + i * 18 + t * 9;   // fusion_w[i][t][kh][kw]
  #pragma unroll
  for (int q = 0; q < 9; ++q) wgt[q] = wp[q];
  float bias = fb[i];
  __syncthreads();
  #pragma unroll
  for (int s0 = 0; s0 < 4; ++s0) {
    int s = tid + s0 * 256;
    int h = s >> 5, w = s & 31;
    float acc = 0.f;
    #pragma unroll
    for (int kh = 0; kh < 3; ++kh) {
      int hh = h + kh - 1;
      if ((unsigned)hh < 32u) {
        #pragma unroll
        for (int kw = 0; kw < 3; ++kw) {
          int ww = w + kw - 1;
          if ((unsigned)ww < 32u) acc += wgt[kh * 3 + kw] * sa[hh * 32 + ww];
        }
      }
    }
    size_t o = ((size_t)bi << 10) + s;
    if (init) M[o] = (bf16)(acc + bias);
    else      M[o] = (bf16)((float)M[o] + acc);
  }
}

// ---- weight reorder+cast: Wr[t][c][d*256+cin] = w_t[c][cin][kh][kw], d = kh*3+kw ----
__global__ void reorder_w(const float* __restrict__ w0, const float* __restrict__ w1,
                          bf16* __restrict__ y) {
  int i = blockIdx.x * 256 + threadIdx.x;   // [0, 2*589824)
  int t = i / 589824, r2 = i % 589824;
  int c = r2 / 2304, r = r2 % 2304;
  int cin = r / 9, d = r % 9;
  y[(size_t)t * 589824 + c * 2304 + d * 256 + cin] = (bf16)(t ? w1 : w0)[r2];
}

// ---------------- NT GEMM: C[m,n] = sum_k A[m,k]*B[n,k], 128xTN tile, MFMA 16x16x32 bf16 ----
// MODE 0: store bf16 C.                                 (dense B, GLL both)
// MODE 2: store fp32 0.5*C + 0.5*feat[t][b].            (dense B, GLL both)
// MODE 3: implicit-conv B staging from fT, bias epilogue. (A GLL; B predicated VGPR path)
// z decode: t = z>>4, b = z&15.
template<int MODE, int TN>
__global__ __launch_bounds__(256)
void gemm_nt(const bf16* __restrict__ A, long long sA,
             const bf16* __restrict__ Bm, long long sB, int K,
             bf16* __restrict__ Cb, long long sC,
             const float* __restrict__ x0, const float* __restrict__ x1,
             float* __restrict__ Co) {
  constexpr int FJ   = (TN == 128) ? 4 : 2;
  constexpr int BSTR = (MODE == 3) ? 72 : 64;
  __shared__ bf16 As[128 * 64];
  __shared__ bf16 Bs[TN * BSTR];
  const int z = blockIdx.z, t = z >> 4;
  const bf16* Ab = A + (size_t)(MODE == 3 ? t : z) * sA;
  const bf16* Bb = Bm + (size_t)(MODE == 2 ? (z & 15) : z) * sB;
  const int m0 = blockIdx.y * 128, n0 = blockIdx.x * TN;
  const int tid = threadIdx.x;
  const int lane = tid & 63, wave = tid >> 6;
  const int wm = (wave >> 1) * 64, wn = (wave & 1) * (TN / 2);
  const int fr = lane & 15, fq = lane >> 4;

  f32x4 acc[4][FJ];
  #pragma unroll
  for (int i = 0; i < 4; ++i)
    #pragma unroll
    for (int j = 0; j < FJ; ++j) acc[i][j] = 0.f;

  for (int k0 = 0; k0 < K; k0 += 64) {
    // ---- A tile: global_load_lds, 16B/lane, unpadded [128][64] ----
    #pragma unroll
    for (int s = 0; s < 4; ++s) {
      int q = (wave * 4 + s) * 64 + lane;         // chunk id in [0,1024)
      int row = q >> 3, col = (q & 7) * 8;
      int lb = __builtin_amdgcn_readfirstlane((wave * 4 + s) * 512);
      gll16(Ab + (size_t)(m0 + row) * K + k0 + col, As + lb);
    }
    // ---- B tile ----
    if (MODE == 3) {
      // implicit im2col: shift d constant within this 64-wide K chunk; OOB rows -> 0
      int d = k0 >> 8;
      int kh = d / 3 - 1, kw = d % 3 - 1;
      int cin0 = k0 & 255;
      #pragma unroll
      for (int s = 0; s < TN / 32; ++s) {
        int q = tid + s * 256;                    // chunk id in [0, TN*8)
        int row = q >> 3, col = (q & 7) * 8;
        int j = n0 + row;
        int h = (j >> 5) + kh, w = (j & 31) + kw;
        float4 v = make_float4(0.f, 0.f, 0.f, 0.f);
        if ((unsigned)h < 32u && (unsigned)w < 32u)
          v = *(const float4*)(Bb + (size_t)(h * 32 + w) * C_ + cin0 + col);
        *(float4*)(&Bs[row * 72 + col]) = v;
      }
    } else {
      #pragma unroll
      for (int s = 0; s < TN / 32; ++s) {
        int q = (wave * (TN / 32) + s) * 64 + lane;
        int row = q >> 3, col = (q & 7) * 8;
        int lb = __builtin_amdgcn_readfirstlane((wave * (TN / 32) + s) * 512);
        gll16(Bb + (size_t)(n0 + row) * K + k0 + col, Bs + lb);
      }
    }
    __syncthreads();
    #pragma unroll
    for (int kk = 0; kk < 64; kk += 32) {
      bf16x8 af[4], bfr[FJ];
      #pragma unroll
      for (int i = 0; i < 4; ++i)
        af[i] = *(const bf16x8*)(&As[(wm + i * 16 + fr) * 64 + kk + fq * 8]);
      #pragma unroll
      for (int j = 0; j < FJ; ++j)
        bfr[j] = *(const bf16x8*)(&Bs[(wn + j * 16 + fr) * BSTR + kk + fq * 8]);
      #pragma unroll
      for (int i = 0; i < 4; ++i)
        #pragma unroll
        for (int j = 0; j < FJ; ++j)
          acc[i][j] = __builtin_amdgcn_mfma_f32_16x16x32_bf16(af[i], bfr[j], acc[i][j], 0, 0, 0);
    }
    __syncthreads();
  }

  // epilogue: D element (reg r, lane) -> row = quad*4 + r, col = lane&15  [m89/m91]
  const float* auxp = t ? x1 : x0;
  #pragma unroll
  for (int i = 0; i < 4; ++i) {
    int rbase = m0 + wm + i * 16 + fq * 4;
    #pragma unroll
    for (int j = 0; j < FJ; ++j) {
      int col = n0 + wn + j * 16 + fr;
      #pragma unroll
      for (int r = 0; r < 4; ++r) {
        int row = rbase + r;
        float v = acc[i][j][r];
        if (MODE == 0) {
          Cb[(size_t)z * sC + (size_t)row * 1024 + col] = (bf16)v;
        } else if (MODE == 3) {
          Cb[(size_t)z * sC + (size_t)row * 1024 + col] = (bf16)(v + auxp[row]);
        } else {
          Co[(size_t)z * sC + (size_t)row * 1024 + col] =
              0.5f * v + 0.5f * auxp[(size_t)(z & 15) * sC + (size_t)row * 1024 + col];
        }
      }
    }
  }
}

extern "C" void kernel_launch(void* const* d_in, const int* in_sizes, int n_in,
                              void* d_out, int out_size, void* d_ws, size_t ws_size,
                              hipStream_t stream) {
  const float* f0 = (const float*)d_in[0];
  const float* f1 = (const float*)d_in[1];
  const float* w0 = (const float*)d_in[2];
  const float* b0 = (const float*)d_in[3];
  const float* w1 = (const float*)d_in[4];
  const float* b1 = (const float*)d_in[5];
  const float* fusion_w = (const float*)d_in[6];
  const float* fusion_b = (const float*)d_in[7];
  float* out = (float*)d_out;

  // workspace layout (~100.8 MB peak; phase2 aliases aff):
  char* ws = (char*)d_ws;
  bf16* Mbuf  = (bf16*)ws;                       // 33,554,432
  bf16* aff   = (bf16*)(ws + 33554432ull);       // 33,554,432 (phase1)
  bf16* Wr    = (bf16*)(ws + 33554432ull);       //  2,359,296 (phase2, aliases aff)
  bf16* value = (bf16*)(ws + 35913728ull);       // 16,777,216 (phase2, aliases aff)
  bf16* Anorm = (bf16*)(ws + 67108864ull);       // 16,777,216 [2 tasks]
  bf16* fT    = (bf16*)(ws + 83886080ull);       // 16,777,216 [2 tasks]
  float* rn   = (float*)(ws + 100663296ull);     //    131,072 [2 tasks]

  rnorm_kernel<<<128, 256, 0, stream>>>(f0, f1, rn);
  transpose_norm<<<dim3(32, 8, 32), dim3(32, 8), 0, stream>>>(f0, f1, rn, Anorm, fT);

  for (int t = 0; t < 2; ++t) {
    const bf16* An = Anorm + (size_t)t * 16 * HW_ * C_;
    // aff[b][i][j] = sum_c An[b][i][c] * An[b][j][c]
    gemm_nt<0, 128><<<dim3(8, 8, 16), 256, 0, stream>>>(
        An, (long long)HW_ * C_, An, (long long)HW_ * C_, C_,
        aff, (long long)HW_ * HW_, nullptr, nullptr, nullptr);
    fusion_conv<<<16384, 256, 0, stream>>>(aff, fusion_w, fusion_b, Mbuf, t, t == 0);
  }

  reorder_w<<<4608, 256, 0, stream>>>(w0, w1, Wr);
  // value[z][c][j] = conv(f_t, w_t)[b][c][j] + bias_t[c]   (z = t*16+b, implicit im2col)
  gemm_nt<3, 64><<<dim3(16, 2, 32), 256, 0, stream>>>(
      Wr, 589824LL, fT, (long long)HW_ * C_, 2304,
      value, (long long)C_ * HW_, b0, b1, nullptr);
  // out[z][c][j] = 0.5 * sum_k value[z][c][k] * Mbuf[b][j][k] + 0.5 * f_t[b][c][j]
  gemm_nt<2, 64><<<dim3(16, 2, 32), 256, 0, stream>>>(
      value, (long long)C_ * HW_, Mbuf, (long long)HW_ * HW_, 1024,
      nullptr, (long long)C_ * HW_, f0, f1, out);
}

// Round 4
// 266.115 us; speedup vs baseline: 1.9896x; 1.2088x over previous
//
#include <hip/hip_runtime.h>
#include <hip/hip_bf16.h>

typedef __bf16 bf16;
typedef __attribute__((ext_vector_type(8))) __bf16 bf16x8;
typedef __attribute__((ext_vector_type(4))) __bf16 bf16x4v;
typedef __attribute__((ext_vector_type(4))) float f32x4;

#define B_  16
#define C_  256
#define HW_ 1024

__device__ __forceinline__ void gll16(const bf16* g, bf16* l) {
  __builtin_amdgcn_global_load_lds((const __attribute__((address_space(1))) void*)g,
                                   (__attribute__((address_space(3))) void*)l, 16, 0, 0);
}

// ---- fused rnorm + transpose: rn[z][k] = 1/||f[z][:,k]||, fT[z][k][c] = bf16(f[z][c][k])
__global__ void prep_kernel(const float* __restrict__ f0, const float* __restrict__ f1,
                            bf16* __restrict__ fT, float* __restrict__ rn) {
  __shared__ float sm[256][33];
  __shared__ float ps[8][32];
  int z = blockIdx.y, t = z >> 4, b = z & 15;
  int k0 = blockIdx.x * 32;
  int tid = threadIdx.x;
  const float* fb = (t ? f1 : f0) + (size_t)b * C_ * HW_ + k0;
  int kk = tid & 31, cg = tid >> 5;
  float ssq = 0.f;
  #pragma unroll
  for (int i = 0; i < 32; ++i) {
    int c = cg + i * 8;
    float v = fb[(size_t)c * HW_ + kk];
    sm[c][kk] = v;
    ssq += v * v;
  }
  ps[cg][kk] = ssq;
  __syncthreads();
  if (tid < 32) {
    float s = 0.f;
    #pragma unroll
    for (int r = 0; r < 8; ++r) s += ps[r][tid];
    rn[z * 1024 + k0 + tid] = 1.f / fmaxf(sqrtf(s), 1e-12f);
  }
  int kl = tid >> 3, c0 = (tid & 7) * 32;
  bf16* dst = fT + ((size_t)z * HW_ + k0 + kl) * C_ + c0;
  #pragma unroll
  for (int u = 0; u < 4; ++u) {
    bf16x8 vv;
    #pragma unroll
    for (int e = 0; e < 8; ++e) vv[e] = (bf16)sm[c0 + u * 8 + e][kl];
    *(bf16x8*)(dst + u * 8) = vv;
  }
}

// ---- grouped 3x3 fusion conv over BOTH tasks, one pass, write Mbuf[b][i][:] ----
__global__ void fusion_conv2(const bf16* __restrict__ aff, const float* __restrict__ fw,
                             const float* __restrict__ fb, bf16* __restrict__ M) {
  __shared__ float sa[2][1024];
  int bi = blockIdx.x;           // b*1024 + i
  int i = bi & 1023, b = bi >> 10;
  int tid = threadIdx.x;
  #pragma unroll
  for (int t = 0; t < 2; ++t) {
    const bf16* arow = aff + (((size_t)t * 16 + b) * 1024 + i) * 1024;
    bf16x4v ch = ((const bf16x4v*)arow)[tid];
    sa[t][tid * 4 + 0] = (float)ch[0];
    sa[t][tid * 4 + 1] = (float)ch[1];
    sa[t][tid * 4 + 2] = (float)ch[2];
    sa[t][tid * 4 + 3] = (float)ch[3];
  }
  float wgt[2][9];
  #pragma unroll
  for (int t = 0; t < 2; ++t)
    #pragma unroll
    for (int q = 0; q < 9; ++q) wgt[t][q] = fw[i * 18 + t * 9 + q];
  float bias = fb[i];
  __syncthreads();
  #pragma unroll
  for (int s0 = 0; s0 < 4; ++s0) {
    int s = tid + s0 * 256;
    int h = s >> 5, w = s & 31;
    float acc = bias;
    #pragma unroll
    for (int kh = 0; kh < 3; ++kh) {
      int hh = h + kh - 1;
      if ((unsigned)hh < 32u) {
        #pragma unroll
        for (int kw = 0; kw < 3; ++kw) {
          int ww = w + kw - 1;
          if ((unsigned)ww < 32u) {
            acc += wgt[0][kh * 3 + kw] * sa[0][hh * 32 + ww];
            acc += wgt[1][kh * 3 + kw] * sa[1][hh * 32 + ww];
          }
        }
      }
    }
    M[((size_t)bi << 10) + s] = (bf16)acc;
  }
}

// ---- weight reorder+cast: Wr[t][c][d*256+cin] = w_t[c][cin][kh][kw], d = kh*3+kw ----
__global__ void reorder_w(const float* __restrict__ w0, const float* __restrict__ w1,
                          bf16* __restrict__ y) {
  int i = blockIdx.x * 256 + threadIdx.x;   // [0, 2*589824)
  int t = i / 589824, r2 = i % 589824;
  int c = r2 / 2304, r = r2 % 2304;
  int cin = r / 9, d = r % 9;
  y[(size_t)t * 589824 + c * 2304 + d * 256 + cin] = (bf16)(t ? w1 : w0)[r2];
}

// ---------------- NT GEMM: C[m,n] = sum_k A[m,k]*B[n,k], 128xTN tile, MFMA 16x16x32 bf16 ----
// GLL tiles use XOR chunk swizzle: physical 16B chunk p = c ^ (row & 7)  -> 2-way max on reads.
// MODE 1: aff SYRK; store bf16 (C * rn[row] * rn[col]).       (dense B, GLL both)
// MODE 2: attend;   store fp32 0.5*C + 0.5*feat[t][b].        (dense B, GLL both)
// MODE 3: value conv; implicit-im2col B from fT (72-pad VGPR path), bias epilogue.
// z decode: t = z>>4, b = z&15.
template<int MODE, int TN>
__global__ __launch_bounds__(256)
void gemm_nt(const bf16* __restrict__ A, long long sA,
             const bf16* __restrict__ Bm, long long sB, int K,
             bf16* __restrict__ Cb, long long sC,
             const float* __restrict__ x0, const float* __restrict__ x1,
             float* __restrict__ Co) {
  constexpr int FJ   = (TN == 128) ? 4 : 2;
  __shared__ bf16 As[128 * 64];
  __shared__ bf16 Bs[TN * ((MODE == 3) ? 72 : 64)];
  const int z = blockIdx.z, t = z >> 4;
  const bf16* Ab = A + (size_t)(MODE == 3 ? t : z) * sA;
  const bf16* Bb = Bm + (size_t)(MODE == 2 ? (z & 15) : z) * sB;
  const int m0 = blockIdx.y * 128, n0 = blockIdx.x * TN;
  const int tid = threadIdx.x;
  const int lane = tid & 63, wave = tid >> 6;
  const int wm = (wave >> 1) * 64, wn = (wave & 1) * (TN / 2);
  const int fr = lane & 15, fq = lane >> 4;

  f32x4 acc[4][FJ];
  #pragma unroll
  for (int i = 0; i < 4; ++i)
    #pragma unroll
    for (int j = 0; j < FJ; ++j) acc[i][j] = 0.f;

  for (int k0 = 0; k0 < K; k0 += 64) {
    // ---- A tile: GLL 16B/lane, swizzled ----
    #pragma unroll
    for (int s = 0; s < 4; ++s) {
      int q = (wave * 4 + s) * 64 + lane;
      int row = q >> 3, c = (q & 7) ^ (row & 7);
      int lb = __builtin_amdgcn_readfirstlane((wave * 4 + s) * 512);
      gll16(Ab + (size_t)(m0 + row) * K + k0 + c * 8, As + lb);
    }
    // ---- B tile ----
    if (MODE == 3) {
      int d = k0 >> 8;
      int kh = d / 3 - 1, kw = d % 3 - 1;
      int cin0 = k0 & 255;
      #pragma unroll
      for (int s = 0; s < TN / 32; ++s) {
        int q = tid + s * 256;
        int row = q >> 3, col = (q & 7) * 8;
        int j = n0 + row;
        int h = (j >> 5) + kh, w = (j & 31) + kw;
        float4 v = make_float4(0.f, 0.f, 0.f, 0.f);
        if ((unsigned)h < 32u && (unsigned)w < 32u)
          v = *(const float4*)(Bb + (size_t)(h * 32 + w) * C_ + cin0 + col);
        *(float4*)(&Bs[row * 72 + col]) = v;
      }
    } else {
      #pragma unroll
      for (int s = 0; s < TN / 32; ++s) {
        int q = (wave * (TN / 32) + s) * 64 + lane;
        int row = q >> 3, c = (q & 7) ^ (row & 7);
        int lb = __builtin_amdgcn_readfirstlane((wave * (TN / 32) + s) * 512);
        gll16(Bb + (size_t)(n0 + row) * K + k0 + c * 8, Bs + lb);
      }
    }
    __syncthreads();
    #pragma unroll
    for (int kk = 0; kk < 64; kk += 32) {
      bf16x8 af[4], bfr[FJ];
      #pragma unroll
      for (int i = 0; i < 4; ++i) {
        int rr = wm + i * 16 + fr;
        int p = ((kk >> 3) + fq) ^ (rr & 7);
        af[i] = *(const bf16x8*)(&As[rr * 64 + p * 8]);
      }
      #pragma unroll
      for (int j = 0; j < FJ; ++j) {
        int rr = wn + j * 16 + fr;
        if (MODE == 3) {
          bfr[j] = *(const bf16x8*)(&Bs[rr * 72 + kk + fq * 8]);
        } else {
          int p = ((kk >> 3) + fq) ^ (rr & 7);
          bfr[j] = *(const bf16x8*)(&Bs[rr * 64 + p * 8]);
        }
      }
      #pragma unroll
      for (int i = 0; i < 4; ++i)
        #pragma unroll
        for (int j = 0; j < FJ; ++j)
          acc[i][j] = __builtin_amdgcn_mfma_f32_16x16x32_bf16(af[i], bfr[j], acc[i][j], 0, 0, 0);
    }
    __syncthreads();
  }

  // epilogue: D element (reg r, lane) -> row = quad*4 + r, col = lane&15  [m89/m91]
  #pragma unroll
  for (int i = 0; i < 4; ++i) {
    int rbase = m0 + wm + i * 16 + fq * 4;
    #pragma unroll
    for (int j = 0; j < FJ; ++j) {
      int col = n0 + wn + j * 16 + fr;
      float cj = (MODE == 1) ? x0[(size_t)z * 1024 + col] : 0.f;
      #pragma unroll
      for (int r = 0; r < 4; ++r) {
        int row = rbase + r;
        float v = acc[i][j][r];
        if (MODE == 1) {
          Cb[(size_t)z * sC + (size_t)row * 1024 + col] =
              (bf16)(v * x0[(size_t)z * 1024 + row] * cj);
        } else if (MODE == 3) {
          const float* bias = t ? x1 : x0;
          Cb[(size_t)z * sC + (size_t)row * 1024 + col] = (bf16)(v + bias[row]);
        } else {
          const float* fp = t ? x1 : x0;
          Co[(size_t)z * sC + (size_t)row * 1024 + col] =
              0.5f * v + 0.5f * fp[(size_t)(z & 15) * sC + (size_t)row * 1024 + col];
        }
      }
    }
  }
}

extern "C" void kernel_launch(void* const* d_in, const int* in_sizes, int n_in,
                              void* d_out, int out_size, void* d_ws, size_t ws_size,
                              hipStream_t stream) {
  const float* f0 = (const float*)d_in[0];
  const float* f1 = (const float*)d_in[1];
  const float* w0 = (const float*)d_in[2];
  const float* b0 = (const float*)d_in[3];
  const float* w1 = (const float*)d_in[4];
  const float* b1 = (const float*)d_in[5];
  const float* fusion_w = (const float*)d_in[6];
  const float* fusion_b = (const float*)d_in[7];
  float* out = (float*)d_out;

  // workspace (~112.1 MB peak; Wr/value alias aff after fusion_conv2 consumes it):
  char* ws = (char*)d_ws;
  bf16* Mbuf  = (bf16*)ws;                       // 33,554,432
  bf16* aff   = (bf16*)(ws + 33554432ull);       // 67,108,864  [2 tasks]
  bf16* Wr    = (bf16*)(ws + 33554432ull);       //  2,359,296  (aliases aff)
  bf16* value = (bf16*)(ws + 35913728ull);       // 16,777,216  (aliases aff)
  bf16* fT    = (bf16*)(ws + 100663296ull);      // 16,777,216  [2 tasks]
  float* rn   = (float*)(ws + 117440512ull);     //    131,072  [2 tasks]

  prep_kernel<<<dim3(32, 32), 256, 0, stream>>>(f0, f1, fT, rn);
  // aff[z][i][j] = (sum_c fT[z][i][c] * fT[z][j][c]) * rn[z][i] * rn[z][j]
  gemm_nt<1, 128><<<dim3(8, 8, 32), 256, 0, stream>>>(
      fT, (long long)HW_ * C_, fT, (long long)HW_ * C_, C_,
      aff, (long long)HW_ * HW_, rn, rn, nullptr);
  fusion_conv2<<<16384, 256, 0, stream>>>(aff, fusion_w, fusion_b, Mbuf);
  reorder_w<<<4608, 256, 0, stream>>>(w0, w1, Wr);
  // value[z][c][j] = conv(f_t, w_t)[b][c][j] + bias_t[c]   (implicit im2col, K=2304)
  gemm_nt<3, 64><<<dim3(16, 2, 32), 256, 0, stream>>>(
      Wr, 589824LL, fT, (long long)HW_ * C_, 2304,
      value, (long long)C_ * HW_, b0, b1, nullptr);
  // out[z][c][j] = 0.5 * sum_k value[z][c][k] * Mbuf[b][j][k] + 0.5 * f_t[b][c][j]
  gemm_nt<2, 64><<<dim3(16, 2, 32), 256, 0, stream>>>(
      value, (long long)C_ * HW_, Mbuf, (long long)HW_ * HW_, 1024,
      nullptr, (long long)C_ * HW_, f0, f1, out);
}

// Round 5
// 263.553 us; speedup vs baseline: 2.0090x; 1.0097x over previous
//
#include <hip/hip_runtime.h>
#include <hip/hip_bf16.h>

typedef __bf16 bf16;
typedef __attribute__((ext_vector_type(8))) __bf16 bf16x8;
typedef __attribute__((ext_vector_type(4))) __bf16 bf16x4v;
typedef __attribute__((ext_vector_type(4))) float f32x4;

#define B_  16
#define C_  256
#define HW_ 1024
#define PADR 1156              // 34*34 padded rows per z
#define ZSTR 295936            // 1156*256 elements per z in fTpad

__device__ __forceinline__ void gll16(const bf16* g, bf16* l) {
  __builtin_amdgcn_global_load_lds((const __attribute__((address_space(1))) void*)g,
                                   (__attribute__((address_space(3))) void*)l, 16, 0, 0);
}

// ---- fused rnorm + transpose into padded layout:
// rn[z][k] = 1/||f[z][:,k]||;  fTpad[z][(h+1)*34+(w+1)][c] = bf16(f[z][c][h*32+w])
__global__ void prep_kernel(const float* __restrict__ f0, const float* __restrict__ f1,
                            bf16* __restrict__ fTpad, float* __restrict__ rn) {
  __shared__ float sm[256][33];
  __shared__ float ps[8][32];
  int z = blockIdx.y, t = z >> 4, b = z & 15;
  int k0 = blockIdx.x * 32;              // h = blockIdx.x, k = k0 + w
  int tid = threadIdx.x;
  const float* fb = (t ? f1 : f0) + (size_t)b * C_ * HW_ + k0;
  int kk = tid & 31, cg = tid >> 5;
  float ssq = 0.f;
  #pragma unroll
  for (int i = 0; i < 32; ++i) {
    int c = cg + i * 8;
    float v = fb[(size_t)c * HW_ + kk];
    sm[c][kk] = v;
    ssq += v * v;
  }
  ps[cg][kk] = ssq;
  __syncthreads();
  if (tid < 32) {
    float s = 0.f;
    #pragma unroll
    for (int r = 0; r < 8; ++r) s += ps[r][tid];
    rn[z * 1024 + k0 + tid] = 1.f / fmaxf(sqrtf(s), 1e-12f);
  }
  int wl = tid >> 3, c0 = (tid & 7) * 32;
  bf16* dst = fTpad + ((size_t)z * PADR + (blockIdx.x + 1) * 34 + wl + 1) * C_ + c0;
  #pragma unroll
  for (int u = 0; u < 4; ++u) {
    bf16x8 vv;
    #pragma unroll
    for (int e = 0; e < 8; ++e) vv[e] = (bf16)sm[c0 + u * 8 + e][wl];
    *(bf16x8*)(dst + u * 8) = vv;
  }
}

// ---- grouped 3x3 fusion conv over BOTH tasks; writes M row (b,i) IN PLACE over aff0 row (b,i)
__global__ void fusion_conv2(const bf16* __restrict__ aff, const float* __restrict__ fw,
                             const float* __restrict__ fb, bf16* __restrict__ M) {
  __shared__ float sa[2][1024];
  int bi = blockIdx.x;           // b*1024 + i
  int i = bi & 1023, b = bi >> 10;
  int tid = threadIdx.x;
  #pragma unroll
  for (int t = 0; t < 2; ++t) {
    const bf16* arow = aff + (((size_t)t * 16 + b) * 1024 + i) * 1024;
    bf16x4v ch = ((const bf16x4v*)arow)[tid];
    sa[t][tid * 4 + 0] = (float)ch[0];
    sa[t][tid * 4 + 1] = (float)ch[1];
    sa[t][tid * 4 + 2] = (float)ch[2];
    sa[t][tid * 4 + 3] = (float)ch[3];
  }
  float wgt[2][9];
  #pragma unroll
  for (int t = 0; t < 2; ++t)
    #pragma unroll
    for (int q = 0; q < 9; ++q) wgt[t][q] = fw[i * 18 + t * 9 + q];
  float bias = fb[i];
  __syncthreads();
  #pragma unroll
  for (int s0 = 0; s0 < 4; ++s0) {
    int s = tid + s0 * 256;
    int h = s >> 5, w = s & 31;
    float acc = bias;
    #pragma unroll
    for (int kh = 0; kh < 3; ++kh) {
      int hh = h + kh - 1;
      if ((unsigned)hh < 32u) {
        #pragma unroll
        for (int kw = 0; kw < 3; ++kw) {
          int ww = w + kw - 1;
          if ((unsigned)ww < 32u) {
            acc += wgt[0][kh * 3 + kw] * sa[0][hh * 32 + ww];
            acc += wgt[1][kh * 3 + kw] * sa[1][hh * 32 + ww];
          }
        }
      }
    }
    M[((size_t)bi << 10) + s] = (bf16)acc;
  }
}

// ---- weight reorder+cast: Wr[t][c][d*256+cin] = w_t[c][cin][kh][kw], d = kh*3+kw ----
__global__ void reorder_w(const float* __restrict__ w0, const float* __restrict__ w1,
                          bf16* __restrict__ y) {
  int i = blockIdx.x * 256 + threadIdx.x;   // [0, 2*589824)
  int t = i / 589824, r2 = i % 589824;
  int c = r2 / 2304, r = r2 % 2304;
  int cin = r / 9, d = r % 9;
  y[(size_t)t * 589824 + c * 2304 + d * 256 + cin] = (bf16)(t ? w1 : w0)[r2];
}

// ---------------- NT GEMM: C[m,n] = sum_k A[m,k]*B[n,k], 128xTN tile, MFMA 16x16x32 bf16 ----
// All tiles staged via global_load_lds with XOR chunk swizzle p = c ^ (row & 7).
// MODE 1: aff SYRK on fTpad rows (padded mapping); store bf16 C * rn[row] * rn[col].
// MODE 2: attend; dense; store fp32 0.5*C + 0.5*feat[t][b].
// MODE 3: value conv; A dense (Wr), B = fTpad with per-d shifted row mapping; +bias.
// z decode: t = z>>4, b = z&15.
template<int MODE, int TN>
__global__ __launch_bounds__(256)
void gemm_nt(const bf16* __restrict__ A, long long sA,
             const bf16* __restrict__ Bm, long long sB, int K,
             bf16* __restrict__ Cb, long long sC,
             const float* __restrict__ x0, const float* __restrict__ x1,
             float* __restrict__ Co) {
  constexpr int FJ = (TN == 128) ? 4 : 2;
  __shared__ bf16 As[128 * 64];
  __shared__ bf16 Bs[TN * 64];
  const int z = blockIdx.z, t = z >> 4;
  const bf16* Ab = A + (size_t)(MODE == 3 ? t : z) * sA;
  const bf16* Bb = Bm + (size_t)(MODE == 2 ? (z & 15) : z) * sB;
  const int m0 = blockIdx.y * 128, n0 = blockIdx.x * TN;
  const int tid = threadIdx.x;
  const int lane = tid & 63, wave = tid >> 6;
  const int wm = (wave >> 1) * 64, wn = (wave & 1) * (TN / 2);
  const int fr = lane & 15, fq = lane >> 4;

  f32x4 acc[4][FJ];
  #pragma unroll
  for (int i = 0; i < 4; ++i)
    #pragma unroll
    for (int j = 0; j < FJ; ++j) acc[i][j] = 0.f;

  for (int k0 = 0; k0 < K; k0 += 64) {
    // ---- A tile: GLL 16B/lane, swizzled ----
    #pragma unroll
    for (int s = 0; s < 4; ++s) {
      int q = (wave * 4 + s) * 64 + lane;
      int row = q >> 3, c = (q & 7) ^ (row & 7);
      int lb = __builtin_amdgcn_readfirstlane((wave * 4 + s) * 512);
      const bf16* src;
      if (MODE == 1) {
        int j = m0 + row;
        src = Ab + (size_t)(((j >> 5) + 1) * 34 + (j & 31) + 1) * C_ + k0 + c * 8;
      } else {
        src = Ab + (size_t)(m0 + row) * K + k0 + c * 8;
      }
      gll16(src, As + lb);
    }
    // ---- B tile: GLL, swizzled; row mapping per MODE ----
    {
      int kh = 0, kw = 0, cin0 = 0;
      if (MODE == 3) {
        int d = k0 >> 8;
        kh = d / 3 - 1; kw = d % 3 - 1; cin0 = k0 & 255;
      }
      #pragma unroll
      for (int s = 0; s < TN / 32; ++s) {
        int q = (wave * (TN / 32) + s) * 64 + lane;
        int row = q >> 3, c = (q & 7) ^ (row & 7);
        int lb = __builtin_amdgcn_readfirstlane((wave * (TN / 32) + s) * 512);
        const bf16* src;
        if (MODE == 3) {
          int j = n0 + row;
          int h = (j >> 5) + kh, w = (j & 31) + kw;
          src = Bb + (size_t)((h + 1) * 34 + (w + 1)) * C_ + cin0 + c * 8;
        } else if (MODE == 1) {
          int j = n0 + row;
          src = Bb + (size_t)(((j >> 5) + 1) * 34 + (j & 31) + 1) * C_ + k0 + c * 8;
        } else {
          src = Bb + (size_t)(n0 + row) * K + k0 + c * 8;
        }
        gll16(src, Bs + lb);
      }
    }
    __syncthreads();
    #pragma unroll
    for (int kk = 0; kk < 64; kk += 32) {
      bf16x8 af[4], bfr[FJ];
      #pragma unroll
      for (int i = 0; i < 4; ++i) {
        int rr = wm + i * 16 + fr;
        int p = ((kk >> 3) + fq) ^ (rr & 7);
        af[i] = *(const bf16x8*)(&As[rr * 64 + p * 8]);
      }
      #pragma unroll
      for (int j = 0; j < FJ; ++j) {
        int rr = wn + j * 16 + fr;
        int p = ((kk >> 3) + fq) ^ (rr & 7);
        bfr[j] = *(const bf16x8*)(&Bs[rr * 64 + p * 8]);
      }
      #pragma unroll
      for (int i = 0; i < 4; ++i)
        #pragma unroll
        for (int j = 0; j < FJ; ++j)
          acc[i][j] = __builtin_amdgcn_mfma_f32_16x16x32_bf16(af[i], bfr[j], acc[i][j], 0, 0, 0);
    }
    __syncthreads();
  }

  // epilogue: D element (reg r, lane) -> row = quad*4 + r, col = lane&15  [m89/m91]
  #pragma unroll
  for (int i = 0; i < 4; ++i) {
    int rbase = m0 + wm + i * 16 + fq * 4;
    #pragma unroll
    for (int j = 0; j < FJ; ++j) {
      int col = n0 + wn + j * 16 + fr;
      float cj = (MODE == 1) ? x0[(size_t)z * 1024 + col] : 0.f;
      #pragma unroll
      for (int r = 0; r < 4; ++r) {
        int row = rbase + r;
        float v = acc[i][j][r];
        if (MODE == 1) {
          Cb[(size_t)z * sC + (size_t)row * 1024 + col] =
              (bf16)(v * x0[(size_t)z * 1024 + row] * cj);
        } else if (MODE == 3) {
          const float* bias = t ? x1 : x0;
          Cb[(size_t)z * sC + (size_t)row * 1024 + col] = (bf16)(v + bias[row]);
        } else {
          const float* fp = t ? x1 : x0;
          Co[(size_t)z * sC + (size_t)row * 1024 + col] =
              0.5f * v + 0.5f * fp[(size_t)(z & 15) * sC + (size_t)row * 1024 + col];
        }
      }
    }
  }
}

extern "C" void kernel_launch(void* const* d_in, const int* in_sizes, int n_in,
                              void* d_out, int out_size, void* d_ws, size_t ws_size,
                              hipStream_t stream) {
  const float* f0 = (const float*)d_in[0];
  const float* f1 = (const float*)d_in[1];
  const float* w0 = (const float*)d_in[2];
  const float* b0 = (const float*)d_in[3];
  const float* w1 = (const float*)d_in[4];
  const float* b1 = (const float*)d_in[5];
  const float* fusion_w = (const float*)d_in[6];
  const float* fusion_b = (const float*)d_in[7];
  float* out = (float*)d_out;

  // workspace (~86.2 MB peak):
  //   aff [2 tasks] at 0..67.1M; Mbuf written IN PLACE over aff0 by fusion_conv2;
  //   Wr + value alias aff1 (consumed before they're written);
  //   fTpad (zero-padded 34x34 layout) and rn live above.
  char* ws = (char*)d_ws;
  bf16* aff   = (bf16*)ws;                       // 67,108,864  [2 tasks]
  bf16* Mbuf  = (bf16*)ws;                       // in-place over aff0
  bf16* Wr    = (bf16*)(ws + 33554432ull);       //  2,359,296  (aliases aff1)
  bf16* value = (bf16*)(ws + 35913728ull);       // 16,777,216  (aliases aff1)
  bf16* fTpad = (bf16*)(ws + 67108864ull);       // 18,939,904
  float* rn   = (float*)(ws + 86048768ull);      //    131,072

  hipMemsetAsync(fTpad, 0, 18939904ull, stream);
  prep_kernel<<<dim3(32, 32), 256, 0, stream>>>(f0, f1, fTpad, rn);
  // aff[z][i][j] = (sum_c fT[z][i][c] * fT[z][j][c]) * rn[z][i] * rn[z][j]
  gemm_nt<1, 128><<<dim3(8, 8, 32), 256, 0, stream>>>(
      fTpad, ZSTR, fTpad, ZSTR, C_,
      aff, (long long)HW_ * HW_, rn, rn, nullptr);
  fusion_conv2<<<16384, 256, 0, stream>>>(aff, fusion_w, fusion_b, Mbuf);
  reorder_w<<<4608, 256, 0, stream>>>(w0, w1, Wr);
  // value[z][c][j] = conv(f_t, w_t)[b][c][j] + bias_t[c]   (implicit im2col, K=2304)
  gemm_nt<3, 64><<<dim3(16, 2, 32), 256, 0, stream>>>(
      Wr, 589824LL, fTpad, ZSTR, 2304,
      value, (long long)C_ * HW_, b0, b1, nullptr);
  // out[z][c][j] = 0.5 * sum_k value[z][c][k] * Mbuf[b][j][k] + 0.5 * f_t[b][c][j]
  gemm_nt<2, 64><<<dim3(16, 2, 32), 256, 0, stream>>>(
      value, (long long)C_ * HW_, Mbuf, (long long)HW_ * HW_, 1024,
      nullptr, (long long)C_ * HW_, f0, f1, out);
}

// Round 6
// 255.102 us; speedup vs baseline: 2.0755x; 1.0331x over previous
//
#include <hip/hip_runtime.h>
#include <hip/hip_bf16.h>

typedef __bf16 bf16;
typedef __attribute__((ext_vector_type(8))) __bf16 bf16x8;
typedef __attribute__((ext_vector_type(4))) __bf16 bf16x4v;
typedef __attribute__((ext_vector_type(4))) float f32x4;

#define B_  16
#define C_  256
#define HW_ 1024
#define PADR 1156              // 34*34 padded rows per z
#define ZSTR 295936            // 1156*256 elements per z in fTpad

__device__ __forceinline__ void gll16(const bf16* g, bf16* l) {
  __builtin_amdgcn_global_load_lds((const __attribute__((address_space(1))) void*)g,
                                   (__attribute__((address_space(3))) void*)l, 16, 0, 0);
}

// ---- fused rnorm + transpose into padded layout:
// rn[z][k] = 1/||f[z][:,k]||;  fTpad[z][(h+1)*34+(w+1)][c] = bf16(f[z][c][h*32+w])
__global__ void prep_kernel(const float* __restrict__ f0, const float* __restrict__ f1,
                            bf16* __restrict__ fTpad, float* __restrict__ rn) {
  __shared__ float sm[256][33];
  __shared__ float ps[8][32];
  int z = blockIdx.y, t = z >> 4, b = z & 15;
  int k0 = blockIdx.x * 32;              // h = blockIdx.x, k = k0 + w
  int tid = threadIdx.x;
  const float* fb = (t ? f1 : f0) + (size_t)b * C_ * HW_ + k0;
  int kk = tid & 31, cg = tid >> 5;
  float ssq = 0.f;
  #pragma unroll
  for (int i = 0; i < 32; ++i) {
    int c = cg + i * 8;
    float v = fb[(size_t)c * HW_ + kk];
    sm[c][kk] = v;
    ssq += v * v;
  }
  ps[cg][kk] = ssq;
  __syncthreads();
  if (tid < 32) {
    float s = 0.f;
    #pragma unroll
    for (int r = 0; r < 8; ++r) s += ps[r][tid];
    rn[z * 1024 + k0 + tid] = 1.f / fmaxf(sqrtf(s), 1e-12f);
  }
  int wl = tid >> 3, c0 = (tid & 7) * 32;
  bf16* dst = fTpad + ((size_t)z * PADR + (blockIdx.x + 1) * 34 + wl + 1) * C_ + c0;
  #pragma unroll
  for (int u = 0; u < 4; ++u) {
    bf16x8 vv;
    #pragma unroll
    for (int e = 0; e < 8; ++e) vv[e] = (bf16)sm[c0 + u * 8 + e][wl];
    *(bf16x8*)(dst + u * 8) = vv;
  }
}

// ---- grouped 3x3 fusion conv over BOTH tasks; writes M row (b,i) IN PLACE over aff0 row (b,i)
__global__ void fusion_conv2(const bf16* __restrict__ aff, const float* __restrict__ fw,
                             const float* __restrict__ fb, bf16* __restrict__ M) {
  __shared__ float sa[2][1024];
  int bi = blockIdx.x;           // b*1024 + i
  int i = bi & 1023, b = bi >> 10;
  int tid = threadIdx.x;
  #pragma unroll
  for (int t = 0; t < 2; ++t) {
    const bf16* arow = aff + (((size_t)t * 16 + b) * 1024 + i) * 1024;
    bf16x4v ch = ((const bf16x4v*)arow)[tid];
    sa[t][tid * 4 + 0] = (float)ch[0];
    sa[t][tid * 4 + 1] = (float)ch[1];
    sa[t][tid * 4 + 2] = (float)ch[2];
    sa[t][tid * 4 + 3] = (float)ch[3];
  }
  float wgt[2][9];
  #pragma unroll
  for (int t = 0; t < 2; ++t)
    #pragma unroll
    for (int q = 0; q < 9; ++q) wgt[t][q] = fw[i * 18 + t * 9 + q];
  float bias = fb[i];
  __syncthreads();
  #pragma unroll
  for (int s0 = 0; s0 < 4; ++s0) {
    int s = tid + s0 * 256;
    int h = s >> 5, w = s & 31;
    float acc = bias;
    #pragma unroll
    for (int kh = 0; kh < 3; ++kh) {
      int hh = h + kh - 1;
      if ((unsigned)hh < 32u) {
        #pragma unroll
        for (int kw = 0; kw < 3; ++kw) {
          int ww = w + kw - 1;
          if ((unsigned)ww < 32u) {
            acc += wgt[0][kh * 3 + kw] * sa[0][hh * 32 + ww];
            acc += wgt[1][kh * 3 + kw] * sa[1][hh * 32 + ww];
          }
        }
      }
    }
    M[((size_t)bi << 10) + s] = (bf16)acc;
  }
}

// ---- weight reorder+cast: Wr[t][c][d*256+cin] = w_t[c][cin][kh][kw], d = kh*3+kw ----
__global__ void reorder_w(const float* __restrict__ w0, const float* __restrict__ w1,
                          bf16* __restrict__ y) {
  int i = blockIdx.x * 256 + threadIdx.x;   // [0, 2*589824)
  int t = i / 589824, r2 = i % 589824;
  int c = r2 / 2304, r = r2 % 2304;
  int cin = r / 9, d = r % 9;
  y[(size_t)t * 589824 + c * 2304 + d * 256 + cin] = (bf16)(t ? w1 : w0)[r2];
}

// ---------------- NT GEMM: C[m,n] = sum_k A[m,k]*B[n,k], 128xTN tile, MFMA 16x16x32 bf16 ----
// All tiles staged via global_load_lds with XOR chunk swizzle p = c ^ (row & 7).
// MODE 1: aff SYRK on fTpad rows; z = t*16+b;  store bf16 C * rn[row] * rn[col].
// MODE 2: attend; z pair-major (t=z&1, b=z>>1): A=value[z], B=Mbuf[b];
//         store fp32 0.5*C + 0.5*feat at task-major offset.
// MODE 3: value conv; z pair-major: A=Wr[t], B=fTpad[t*16+b] shifted rows; +bias; C=value[z].
template<int MODE, int TN>
__global__ __launch_bounds__(256)
void gemm_nt(const bf16* __restrict__ A, long long sA,
             const bf16* __restrict__ Bm, long long sB, int K,
             bf16* __restrict__ Cb, long long sC,
             const float* __restrict__ x0, const float* __restrict__ x1,
             float* __restrict__ Co) {
  constexpr int FJ = (TN == 128) ? 4 : 2;
  __shared__ bf16 As[128 * 64];
  __shared__ bf16 Bs[TN * 64];
  const int z = blockIdx.z;
  const int tt = (MODE == 1) ? (z >> 4) : (z & 1);
  const int bb = (MODE == 1) ? (z & 15) : (z >> 1);
  const int zold = tt * 16 + bb;
  const bf16* Ab = A + (size_t)(MODE == 3 ? tt : z) * sA;
  const bf16* Bb = Bm + (size_t)(MODE == 1 ? z : (MODE == 2 ? bb : zold)) * sB;
  const int m0 = blockIdx.y * 128, n0 = blockIdx.x * TN;
  const int tid = threadIdx.x;
  const int lane = tid & 63, wave = tid >> 6;
  const int wm = (wave >> 1) * 64, wn = (wave & 1) * (TN / 2);
  const int fr = lane & 15, fq = lane >> 4;

  f32x4 acc[4][FJ];
  #pragma unroll
  for (int i = 0; i < 4; ++i)
    #pragma unroll
    for (int j = 0; j < FJ; ++j) acc[i][j] = 0.f;

  for (int k0 = 0; k0 < K; k0 += 64) {
    // ---- A tile: GLL 16B/lane, swizzled ----
    #pragma unroll
    for (int s = 0; s < 4; ++s) {
      int q = (wave * 4 + s) * 64 + lane;
      int row = q >> 3, c = (q & 7) ^ (row & 7);
      int lb = __builtin_amdgcn_readfirstlane((wave * 4 + s) * 512);
      const bf16* src;
      if (MODE == 1) {
        int j = m0 + row;
        src = Ab + (size_t)(((j >> 5) + 1) * 34 + (j & 31) + 1) * C_ + k0 + c * 8;
      } else {
        src = Ab + (size_t)(m0 + row) * K + k0 + c * 8;
      }
      gll16(src, As + lb);
    }
    // ---- B tile: GLL, swizzled; row mapping per MODE ----
    {
      int kh = 0, kw = 0, cin0 = 0;
      if (MODE == 3) {
        int d = k0 >> 8;
        kh = d / 3 - 1; kw = d % 3 - 1; cin0 = k0 & 255;
      }
      #pragma unroll
      for (int s = 0; s < TN / 32; ++s) {
        int q = (wave * (TN / 32) + s) * 64 + lane;
        int row = q >> 3, c = (q & 7) ^ (row & 7);
        int lb = __builtin_amdgcn_readfirstlane((wave * (TN / 32) + s) * 512);
        const bf16* src;
        if (MODE == 3) {
          int j = n0 + row;
          int h = (j >> 5) + kh, w = (j & 31) + kw;
          src = Bb + (size_t)((h + 1) * 34 + (w + 1)) * C_ + cin0 + c * 8;
        } else if (MODE == 1) {
          int j = n0 + row;
          src = Bb + (size_t)(((j >> 5) + 1) * 34 + (j & 31) + 1) * C_ + k0 + c * 8;
        } else {
          src = Bb + (size_t)(n0 + row) * K + k0 + c * 8;
        }
        gll16(src, Bs + lb);
      }
    }
    __syncthreads();
    #pragma unroll
    for (int kk = 0; kk < 64; kk += 32) {
      bf16x8 af[4], bfr[FJ];
      #pragma unroll
      for (int i = 0; i < 4; ++i) {
        int rr = wm + i * 16 + fr;
        int p = ((kk >> 3) + fq) ^ (rr & 7);
        af[i] = *(const bf16x8*)(&As[rr * 64 + p * 8]);
      }
      #pragma unroll
      for (int j = 0; j < FJ; ++j) {
        int rr = wn + j * 16 + fr;
        int p = ((kk >> 3) + fq) ^ (rr & 7);
        bfr[j] = *(const bf16x8*)(&Bs[rr * 64 + p * 8]);
      }
      #pragma unroll
      for (int i = 0; i < 4; ++i)
        #pragma unroll
        for (int j = 0; j < FJ; ++j)
          acc[i][j] = __builtin_amdgcn_mfma_f32_16x16x32_bf16(af[i], bfr[j], acc[i][j], 0, 0, 0);
    }
    __syncthreads();
  }

  // epilogue: D element (reg r, lane) -> row = quad*4 + r, col = lane&15  [m89/m91]
  #pragma unroll
  for (int i = 0; i < 4; ++i) {
    int rbase = m0 + wm + i * 16 + fq * 4;
    #pragma unroll
    for (int j = 0; j < FJ; ++j) {
      int col = n0 + wn + j * 16 + fr;
      float cj = (MODE == 1) ? x0[(size_t)z * 1024 + col] : 0.f;
      #pragma unroll
      for (int r = 0; r < 4; ++r) {
        int row = rbase + r;
        float v = acc[i][j][r];
        if (MODE == 1) {
          Cb[(size_t)z * sC + (size_t)row * 1024 + col] =
              (bf16)(v * x0[(size_t)z * 1024 + row] * cj);
        } else if (MODE == 3) {
          const float* bias = tt ? x1 : x0;
          Cb[(size_t)z * sC + (size_t)row * 1024 + col] = (bf16)(v + bias[row]);
        } else {
          const float* fp = tt ? x1 : x0;
          Co[(size_t)zold * sC + (size_t)row * 1024 + col] =
              0.5f * v + 0.5f * fp[(size_t)bb * sC + (size_t)row * 1024 + col];
        }
      }
    }
  }
}

extern "C" void kernel_launch(void* const* d_in, const int* in_sizes, int n_in,
                              void* d_out, int out_size, void* d_ws, size_t ws_size,
                              hipStream_t stream) {
  const float* f0 = (const float*)d_in[0];
  const float* f1 = (const float*)d_in[1];
  const float* w0 = (const float*)d_in[2];
  const float* b0 = (const float*)d_in[3];
  const float* w1 = (const float*)d_in[4];
  const float* b1 = (const float*)d_in[5];
  const float* fusion_w = (const float*)d_in[6];
  const float* fusion_b = (const float*)d_in[7];
  float* out = (float*)d_out;

  // workspace (~86.2 MB peak):
  //   aff [2 tasks] at 0..67.1M; Mbuf written IN PLACE over aff0 by fusion_conv2;
  //   Wr + value alias aff1 (consumed before they're written);
  //   fTpad (zero-padded 34x34 layout) and rn live above.
  char* ws = (char*)d_ws;
  bf16* aff   = (bf16*)ws;                       // 67,108,864  [2 tasks]
  bf16* Mbuf  = (bf16*)ws;                       // in-place over aff0
  bf16* Wr    = (bf16*)(ws + 33554432ull);       //  2,359,296  (aliases aff1)
  bf16* value = (bf16*)(ws + 35913728ull);       // 16,777,216  (aliases aff1)
  bf16* fTpad = (bf16*)(ws + 67108864ull);       // 18,939,904
  float* rn   = (float*)(ws + 86048768ull);      //    131,072

  hipMemsetAsync(fTpad, 0, 18939904ull, stream);
  prep_kernel<<<dim3(32, 32), 256, 0, stream>>>(f0, f1, fTpad, rn);
  // aff[z][i][j] = (sum_c fT[z][i][c] * fT[z][j][c]) * rn[z][i] * rn[z][j]
  gemm_nt<1, 128><<<dim3(8, 8, 32), 256, 0, stream>>>(
      fTpad, ZSTR, fTpad, ZSTR, C_,
      aff, (long long)HW_ * HW_, rn, rn, nullptr);
  fusion_conv2<<<16384, 256, 0, stream>>>(aff, fusion_w, fusion_b, Mbuf);
  reorder_w<<<4608, 256, 0, stream>>>(w0, w1, Wr);
  // value[zp][c][j] = conv(f_t, w_t)[b][c][j] + bias_t[c]   (zp pair-major: t=zp&1, b=zp>>1)
  gemm_nt<3, 128><<<dim3(8, 2, 32), 256, 0, stream>>>(
      Wr, 589824LL, fTpad, ZSTR, 2304,
      value, (long long)C_ * HW_, b0, b1, nullptr);
  // out[t][b][c][j] = 0.5 * sum_k value[zp][c][k] * Mbuf[b][j][k] + 0.5 * f_t[b][c][j]
  gemm_nt<2, 128><<<dim3(8, 2, 32), 256, 0, stream>>>(
      value, (long long)C_ * HW_, Mbuf, (long long)HW_ * HW_, 1024,
      nullptr, (long long)C_ * HW_, f0, f1, out);
}

// Round 7
// 239.797 us; speedup vs baseline: 2.2080x; 1.0638x over previous
//
#include <hip/hip_runtime.h>
#include <hip/hip_bf16.h>

typedef __bf16 bf16;
typedef __attribute__((ext_vector_type(8))) __bf16 bf16x8;
typedef __attribute__((ext_vector_type(4))) __bf16 bf16x4v;
typedef __attribute__((ext_vector_type(4))) float f32x4;

#define B_  16
#define C_  256
#define HW_ 1024
#define PADR 1156              // 34*34 padded rows per z
#define ZSTR 295936            // 1156*256 elements per z in fTpad

__device__ __forceinline__ void gll16(const bf16* g, bf16* l) {
  __builtin_amdgcn_global_load_lds((const __attribute__((address_space(1))) void*)g,
                                   (__attribute__((address_space(3))) void*)l, 16, 0, 0);
}

// ---- fused rnorm + transpose into padded layout (borders zeroed here; no memset):
// rn[z][k] = 1/||f[z][:,k]||;  fTpad[z][(h+1)*34+(w+1)][c] = bf16(f[z][c][h*32+w])
__global__ void prep_kernel(const float* __restrict__ f0, const float* __restrict__ f1,
                            bf16* __restrict__ fTpad, float* __restrict__ rn) {
  __shared__ float sm[256][33];
  __shared__ float ps[8][32];
  int z = blockIdx.y, t = z >> 4, b = z & 15;
  int k0 = blockIdx.x * 32;              // h = blockIdx.x, k = k0 + w
  int tid = threadIdx.x;
  const float* fb = (t ? f1 : f0) + (size_t)b * C_ * HW_ + k0;
  int kk = tid & 31, cg = tid >> 5;
  float ssq = 0.f;
  #pragma unroll
  for (int i = 0; i < 32; ++i) {
    int c = cg + i * 8;
    float v = fb[(size_t)c * HW_ + kk];
    sm[c][kk] = v;
    ssq += v * v;
  }
  ps[cg][kk] = ssq;

  bf16x8 zv;
  #pragma unroll
  for (int e = 0; e < 8; ++e) zv[e] = (bf16)0.f;
  // zero borders of this block's padded row (w=0 and w=33)
  if (tid < 64) {
    int c = (tid & 31) * 8, side = tid >> 5;
    *(bf16x8*)(fTpad + ((size_t)z * PADR + (blockIdx.x + 1) * 34 + side * 33) * C_ + c) = zv;
  }
  // blocks 0/31 also zero the full top/bottom padded rows
  if (blockIdx.x == 0 || blockIdx.x == 31) {
    int prow = (blockIdx.x == 0) ? 0 : 33;
    for (int q = tid; q < 34 * 32; q += 256) {
      int wcol = q >> 5, c = (q & 31) * 8;
      *(bf16x8*)(fTpad + ((size_t)z * PADR + prow * 34 + wcol) * C_ + c) = zv;
    }
  }

  __syncthreads();
  if (tid < 32) {
    float s = 0.f;
    #pragma unroll
    for (int r = 0; r < 8; ++r) s += ps[r][tid];
    rn[z * 1024 + k0 + tid] = 1.f / fmaxf(sqrtf(s), 1e-12f);
  }
  int wl = tid >> 3, c0 = (tid & 7) * 32;
  bf16* dst = fTpad + ((size_t)z * PADR + (blockIdx.x + 1) * 34 + wl + 1) * C_ + c0;
  #pragma unroll
  for (int u = 0; u < 4; ++u) {
    bf16x8 vv;
    #pragma unroll
    for (int e = 0; e < 8; ++e) vv[e] = (bf16)sm[c0 + u * 8 + e][wl];
    *(bf16x8*)(dst + u * 8) = vv;
  }
}

// ---- grouped 3x3 fusion conv over BOTH tasks; writes M row (b,i) IN PLACE over aff0 row (b,i)
__global__ void fusion_conv2(const bf16* __restrict__ aff, const float* __restrict__ fw,
                             const float* __restrict__ fb, bf16* __restrict__ M) {
  __shared__ float sa[2][1024];
  int bi = blockIdx.x;           // b*1024 + i
  int i = bi & 1023, b = bi >> 10;
  int tid = threadIdx.x;
  #pragma unroll
  for (int t = 0; t < 2; ++t) {
    const bf16* arow = aff + (((size_t)t * 16 + b) * 1024 + i) * 1024;
    bf16x4v ch = ((const bf16x4v*)arow)[tid];
    sa[t][tid * 4 + 0] = (float)ch[0];
    sa[t][tid * 4 + 1] = (float)ch[1];
    sa[t][tid * 4 + 2] = (float)ch[2];
    sa[t][tid * 4 + 3] = (float)ch[3];
  }
  float wgt[2][9];
  #pragma unroll
  for (int t = 0; t < 2; ++t)
    #pragma unroll
    for (int q = 0; q < 9; ++q) wgt[t][q] = fw[i * 18 + t * 9 + q];
  float bias = fb[i];
  __syncthreads();
  #pragma unroll
  for (int s0 = 0; s0 < 4; ++s0) {
    int s = tid + s0 * 256;
    int h = s >> 5, w = s & 31;
    float acc = bias;
    #pragma unroll
    for (int kh = 0; kh < 3; ++kh) {
      int hh = h + kh - 1;
      if ((unsigned)hh < 32u) {
        #pragma unroll
        for (int kw = 0; kw < 3; ++kw) {
          int ww = w + kw - 1;
          if ((unsigned)ww < 32u) {
            acc += wgt[0][kh * 3 + kw] * sa[0][hh * 32 + ww];
            acc += wgt[1][kh * 3 + kw] * sa[1][hh * 32 + ww];
          }
        }
      }
    }
    M[((size_t)bi << 10) + s] = (bf16)acc;
  }
}

// ---- weight reorder+cast: Wr[t][c][d*256+cin] = w_t[c][cin][kh][kw], d = kh*3+kw ----
__global__ void reorder_w(const float* __restrict__ w0, const float* __restrict__ w1,
                          bf16* __restrict__ y) {
  int i = blockIdx.x * 256 + threadIdx.x;   // [0, 2*589824)
  int t = i / 589824, r2 = i % 589824;
  int c = r2 / 2304, r = r2 % 2304;
  int cin = r / 9, d = r % 9;
  y[(size_t)t * 589824 + c * 2304 + d * 256 + cin] = (bf16)(t ? w1 : w0)[r2];
}

// ---------------- NT GEMM: C[m,n] = sum_k A[m,k]*B[n,k], 128x128 tile, MFMA 16x16x32 bf16 ----
// All tiles staged via global_load_lds with XOR chunk swizzle p = c ^ (row & 7).
// Per-lane source base pointers hoisted out of the K-loop; per-iter offset is wave-uniform.
// MODE 1: aff SYRK on fTpad rows; z = t*16+b;  store bf16 C * rn[row] * rn[col].
// MODE 2: attend; z pair-major (t=z&1, b=z>>1): A=value[z], B=Mbuf[b];
//         store fp32 0.5*C + 0.5*feat at task-major offset.
// MODE 3: value conv; z pair-major: A=Wr[t], B=fTpad[t*16+b] shifted rows; +bias; C=value[z].
template<int MODE>
__global__ __launch_bounds__(256, 4)
void gemm_nt(const bf16* __restrict__ A, long long sA,
             const bf16* __restrict__ Bm, long long sB, int K,
             bf16* __restrict__ Cb, long long sC,
             const float* __restrict__ x0, const float* __restrict__ x1,
             float* __restrict__ Co) {
  __shared__ bf16 As[128 * 64];
  __shared__ bf16 Bs[128 * 64];
  const int z = blockIdx.z;
  const int tt = (MODE == 1) ? (z >> 4) : (z & 1);
  const int bb = (MODE == 1) ? (z & 15) : (z >> 1);
  const int zold = tt * 16 + bb;
  const bf16* Ab = A + (size_t)(MODE == 3 ? tt : z) * sA;
  const bf16* Bb = Bm + (size_t)(MODE == 1 ? z : (MODE == 2 ? bb : zold)) * sB;
  const int m0 = blockIdx.y * 128, n0 = blockIdx.x * 128;
  const int tid = threadIdx.x;
  const int lane = tid & 63, wave = tid >> 6;
  const int wm = (wave >> 1) * 64, wn = (wave & 1) * 64;
  const int fr = lane & 15, fq = lane >> 4;

  // ---- hoisted per-lane global source bases + fixed LDS destinations ----
  const bf16* srcA[4];
  const bf16* srcB[4];
  int ldsA[4], ldsB[4];
  #pragma unroll
  for (int s = 0; s < 4; ++s) {
    int q = (wave * 4 + s) * 64 + lane;
    int row = q >> 3, c = (q & 7) ^ (row & 7);
    ldsA[s] = ldsB[s] = __builtin_amdgcn_readfirstlane((wave * 4 + s) * 512);
    if (MODE == 1) {
      int j = m0 + row;
      srcA[s] = Ab + (size_t)(((j >> 5) + 1) * 34 + (j & 31) + 1) * C_ + c * 8;
    } else {
      srcA[s] = Ab + (size_t)(m0 + row) * K + c * 8;
    }
    int jb = n0 + row;
    if (MODE == 1) {
      srcB[s] = Bb + (size_t)(((jb >> 5) + 1) * 34 + (jb & 31) + 1) * C_ + c * 8;
    } else if (MODE == 3) {
      // center (d=4) base; per-iter scalar offset supplies the (kh,kw) shift
      srcB[s] = Bb + (size_t)(((jb >> 5) + 1) * 34 + (jb & 31) + 1) * C_ + c * 8;
    } else {
      srcB[s] = Bb + (size_t)jb * K + c * 8;
    }
  }
  // ---- hoisted LDS fragment offsets (both kk halves) ----
  int lA[2][4], lB[2][4];
  #pragma unroll
  for (int h = 0; h < 2; ++h) {
    #pragma unroll
    for (int i = 0; i < 4; ++i) {
      int rr = wm + i * 16 + fr;
      lA[h][i] = rr * 64 + (((h * 4) + fq) ^ (rr & 7)) * 8;
      int rc = wn + i * 16 + fr;
      lB[h][i] = rc * 64 + (((h * 4) + fq) ^ (rc & 7)) * 8;
    }
  }

  f32x4 acc[4][4];
  #pragma unroll
  for (int i = 0; i < 4; ++i)
    #pragma unroll
    for (int j = 0; j < 4; ++j) acc[i][j] = 0.f;

  for (int k0 = 0; k0 < K; k0 += 64) {
    int boff;
    if (MODE == 3) {
      int d = k0 >> 8;
      int kh = d / 3, kw = d % 3;                       // 0..2
      boff = ((kh - 1) * 34 + (kw - 1)) * C_ + (k0 & 255);
    } else {
      boff = k0;
    }
    #pragma unroll
    for (int s = 0; s < 4; ++s) gll16(srcA[s] + k0, As + ldsA[s]);
    #pragma unroll
    for (int s = 0; s < 4; ++s) gll16(srcB[s] + boff, Bs + ldsB[s]);
    __syncthreads();
    #pragma unroll
    for (int h = 0; h < 2; ++h) {
      bf16x8 af[4], bfr[4];
      #pragma unroll
      for (int i = 0; i < 4; ++i) af[i] = *(const bf16x8*)(&As[lA[h][i]]);
      #pragma unroll
      for (int j = 0; j < 4; ++j) bfr[j] = *(const bf16x8*)(&Bs[lB[h][j]]);
      #pragma unroll
      for (int i = 0; i < 4; ++i)
        #pragma unroll
        for (int j = 0; j < 4; ++j)
          acc[i][j] = __builtin_amdgcn_mfma_f32_16x16x32_bf16(af[i], bfr[j], acc[i][j], 0, 0, 0);
    }
    __syncthreads();
  }

  // epilogue: D element (reg r, lane) -> row = quad*4 + r, col = lane&15  [m89/m91]
  #pragma unroll
  for (int i = 0; i < 4; ++i) {
    int rbase = m0 + wm + i * 16 + fq * 4;
    #pragma unroll
    for (int j = 0; j < 4; ++j) {
      int col = n0 + wn + j * 16 + fr;
      float cj = (MODE == 1) ? x0[(size_t)z * 1024 + col] : 0.f;
      #pragma unroll
      for (int r = 0; r < 4; ++r) {
        int row = rbase + r;
        float v = acc[i][j][r];
        if (MODE == 1) {
          Cb[(size_t)z * sC + (size_t)row * 1024 + col] =
              (bf16)(v * x0[(size_t)z * 1024 + row] * cj);
        } else if (MODE == 3) {
          const float* bias = tt ? x1 : x0;
          Cb[(size_t)z * sC + (size_t)row * 1024 + col] = (bf16)(v + bias[row]);
        } else {
          const float* fp = tt ? x1 : x0;
          Co[(size_t)zold * sC + (size_t)row * 1024 + col] =
              0.5f * v + 0.5f * fp[(size_t)bb * sC + (size_t)row * 1024 + col];
        }
      }
    }
  }
}

extern "C" void kernel_launch(void* const* d_in, const int* in_sizes, int n_in,
                              void* d_out, int out_size, void* d_ws, size_t ws_size,
                              hipStream_t stream) {
  const float* f0 = (const float*)d_in[0];
  const float* f1 = (const float*)d_in[1];
  const float* w0 = (const float*)d_in[2];
  const float* b0 = (const float*)d_in[3];
  const float* w1 = (const float*)d_in[4];
  const float* b1 = (const float*)d_in[5];
  const float* fusion_w = (const float*)d_in[6];
  const float* fusion_b = (const float*)d_in[7];
  float* out = (float*)d_out;

  // workspace (~86.2 MB peak):
  //   aff [2 tasks] at 0..67.1M; Mbuf written IN PLACE over aff0 by fusion_conv2;
  //   Wr + value alias aff1 (consumed before they're written);
  //   fTpad (zero-padded 34x34 layout, borders zeroed by prep) and rn above.
  char* ws = (char*)d_ws;
  bf16* aff   = (bf16*)ws;                       // 67,108,864  [2 tasks]
  bf16* Mbuf  = (bf16*)ws;                       // in-place over aff0
  bf16* Wr    = (bf16*)(ws + 33554432ull);       //  2,359,296  (aliases aff1)
  bf16* value = (bf16*)(ws + 35913728ull);       // 16,777,216  (aliases aff1)
  bf16* fTpad = (bf16*)(ws + 67108864ull);       // 18,939,904
  float* rn   = (float*)(ws + 86048768ull);      //    131,072

  prep_kernel<<<dim3(32, 32), 256, 0, stream>>>(f0, f1, fTpad, rn);
  // aff[z][i][j] = (sum_c fT[z][i][c] * fT[z][j][c]) * rn[z][i] * rn[z][j]
  gemm_nt<1><<<dim3(8, 8, 32), 256, 0, stream>>>(
      fTpad, ZSTR, fTpad, ZSTR, C_,
      aff, (long long)HW_ * HW_, rn, rn, nullptr);
  fusion_conv2<<<16384, 256, 0, stream>>>(aff, fusion_w, fusion_b, Mbuf);
  reorder_w<<<4608, 256, 0, stream>>>(w0, w1, Wr);
  // value[zp][c][j] = conv(f_t, w_t)[b][c][j] + bias_t[c]   (zp pair-major: t=zp&1, b=zp>>1)
  gemm_nt<3><<<dim3(8, 2, 32), 256, 0, stream>>>(
      Wr, 589824LL, fTpad, ZSTR, 2304,
      value, (long long)C_ * HW_, b0, b1, nullptr);
  // out[t][b][c][j] = 0.5 * sum_k value[zp][c][k] * Mbuf[b][j][k] + 0.5 * f_t[b][c][j]
  gemm_nt<2><<<dim3(8, 2, 32), 256, 0, stream>>>(
      value, (long long)C_ * HW_, Mbuf, (long long)HW_ * HW_, 1024,
      nullptr, (long long)C_ * HW_, f0, f1, out);
}